// Round 1
// baseline (174.421 us; speedup 1.0000x reference)
//
#include <hip/hip_runtime.h>

#define B_ 4
#define QN 512
#define KVN 512
#define QD_ 512
#define H_ 256
#define VD_ 256

// tanh(x) = 1 - 2/(exp2(2*log2e*x) + 1)  -- exact; saturates correctly at +-inf
__device__ __forceinline__ float fast_tanh(float x) {
    float e = __builtin_amdgcn_exp2f(x * 2.8853900817779268f);
    float r = __builtin_amdgcn_rcpf(e + 1.0f);
    return __builtin_fmaf(-2.0f, r, 1.0f);
}

// ---------------- K1: projection GEMM  C[r][h] = sum_d A[r][d] * W[h][d] ----------------
// A: [2048][512], W: [256][512], C: [2048][256]
__global__ __launch_bounds__(256) void proj_nt(const float* __restrict__ A,
                                               const float* __restrict__ W,
                                               float* __restrict__ C) {
    const int BK = 16;
    __shared__ float As[BK][68];  // As[kk][m] = A[r0+m][k0+kk], pad->68 keeps rows 16B aligned
    __shared__ float Ws[BK][68];  // Ws[kk][n] = W[h0+n][k0+kk]
    int r0 = blockIdx.y * 64;
    int h0 = blockIdx.x * 64;
    int tid = threadIdx.x;
    int tm = tid >> 4, tn = tid & 15;
    float c[4][4] = {};
    for (int k0 = 0; k0 < QD_; k0 += BK) {
#pragma unroll
        for (int i = 0; i < 4; ++i) {
            int l = tid + i * 256;
            int m = l >> 4, kk = l & 15;
            As[kk][m] = A[(size_t)(r0 + m) * QD_ + k0 + kk];
            Ws[kk][m] = W[(size_t)(h0 + m) * QD_ + k0 + kk];
        }
        __syncthreads();
#pragma unroll
        for (int kk = 0; kk < BK; ++kk) {
            float4 a = *(const float4*)&As[kk][tm * 4];
            float4 b = *(const float4*)&Ws[kk][tn * 4];
            c[0][0] = __builtin_fmaf(a.x, b.x, c[0][0]);
            c[0][1] = __builtin_fmaf(a.x, b.y, c[0][1]);
            c[0][2] = __builtin_fmaf(a.x, b.z, c[0][2]);
            c[0][3] = __builtin_fmaf(a.x, b.w, c[0][3]);
            c[1][0] = __builtin_fmaf(a.y, b.x, c[1][0]);
            c[1][1] = __builtin_fmaf(a.y, b.y, c[1][1]);
            c[1][2] = __builtin_fmaf(a.y, b.z, c[1][2]);
            c[1][3] = __builtin_fmaf(a.y, b.w, c[1][3]);
            c[2][0] = __builtin_fmaf(a.z, b.x, c[2][0]);
            c[2][1] = __builtin_fmaf(a.z, b.y, c[2][1]);
            c[2][2] = __builtin_fmaf(a.z, b.z, c[2][2]);
            c[2][3] = __builtin_fmaf(a.z, b.w, c[2][3]);
            c[3][0] = __builtin_fmaf(a.w, b.x, c[3][0]);
            c[3][1] = __builtin_fmaf(a.w, b.y, c[3][1]);
            c[3][2] = __builtin_fmaf(a.w, b.z, c[3][2]);
            c[3][3] = __builtin_fmaf(a.w, b.w, c[3][3]);
        }
        __syncthreads();
    }
#pragma unroll
    for (int ii = 0; ii < 4; ++ii) {
        float4 r;
        r.x = c[ii][0]; r.y = c[ii][1]; r.z = c[ii][2]; r.w = c[ii][3];
        *(float4*)&C[(size_t)(r0 + tm * 4 + ii) * H_ + h0 + tn * 4] = r;
    }
}

// ---------------- K2: scores[b][i][j] = sum_h wv[h] * tanh(qh[b][i][h] + kh[b][j][h]) ----
__global__ __launch_bounds__(256) void scores_kernel(const float* __restrict__ qh,
                                                     const float* __restrict__ kh,
                                                     const float* __restrict__ wv,
                                                     float* __restrict__ sc) {
    const int TQ = 32, TK = 64, HC = 64;
    __shared__ float qs[TQ][HC + 1];
    __shared__ float ks[TK][HC + 1];
    __shared__ float wvs[H_];
    int b = blockIdx.z;
    int i0 = blockIdx.y * TQ;
    int j0 = blockIdx.x * TK;
    int tid = threadIdx.x;
    int ti = tid >> 4, tj = tid & 15;
    wvs[tid] = wv[tid];  // blockDim == H_ == 256
    float acc[2][4] = {};
    for (int h0 = 0; h0 < H_; h0 += HC) {
#pragma unroll
        for (int t = 0; t < 8; ++t) {  // 32x64 qh tile
            int l = tid + t * 256;
            int row = l >> 6, hh = l & 63;
            qs[row][hh] = qh[(size_t)(b * QN + i0 + row) * H_ + h0 + hh];
        }
#pragma unroll
        for (int t = 0; t < 16; ++t) {  // 64x64 kh tile
            int l = tid + t * 256;
            int row = l >> 6, hh = l & 63;
            ks[row][hh] = kh[(size_t)(b * KVN + j0 + row) * H_ + h0 + hh];
        }
        __syncthreads();
        for (int h = 0; h < HC; ++h) {
            float w = wvs[h0 + h];
            float qa0 = qs[ti][h];
            float qa1 = qs[ti + 16][h];
            float kb0 = ks[tj][h];
            float kb1 = ks[tj + 16][h];
            float kb2 = ks[tj + 32][h];
            float kb3 = ks[tj + 48][h];
            acc[0][0] = __builtin_fmaf(w, fast_tanh(qa0 + kb0), acc[0][0]);
            acc[0][1] = __builtin_fmaf(w, fast_tanh(qa0 + kb1), acc[0][1]);
            acc[0][2] = __builtin_fmaf(w, fast_tanh(qa0 + kb2), acc[0][2]);
            acc[0][3] = __builtin_fmaf(w, fast_tanh(qa0 + kb3), acc[0][3]);
            acc[1][0] = __builtin_fmaf(w, fast_tanh(qa1 + kb0), acc[1][0]);
            acc[1][1] = __builtin_fmaf(w, fast_tanh(qa1 + kb1), acc[1][1]);
            acc[1][2] = __builtin_fmaf(w, fast_tanh(qa1 + kb2), acc[1][2]);
            acc[1][3] = __builtin_fmaf(w, fast_tanh(qa1 + kb3), acc[1][3]);
        }
        __syncthreads();
    }
#pragma unroll
    for (int ii = 0; ii < 2; ++ii)
#pragma unroll
        for (int jj = 0; jj < 4; ++jj)
            sc[(size_t)(b * QN + i0 + ti + 16 * ii) * KVN + j0 + tj + 16 * jj] = acc[ii][jj];
}

// ---------------- K3: in-place softmax over last dim (512) ----------------
__global__ __launch_bounds__(256) void softmax_kernel(float* __restrict__ attn) {
    int row = blockIdx.x;
    int tid = threadIdx.x;
    float* p = attn + (size_t)row * KVN;
    float x0 = p[tid], x1 = p[tid + 256];
    float m = fmaxf(x0, x1);
#pragma unroll
    for (int d = 1; d < 64; d <<= 1) m = fmaxf(m, __shfl_xor(m, d));
    __shared__ float redm[4], reds[4];
    int wave = tid >> 6, lane = tid & 63;
    if (lane == 0) redm[wave] = m;
    __syncthreads();
    m = fmaxf(fmaxf(redm[0], redm[1]), fmaxf(redm[2], redm[3]));
    float e0 = __expf(x0 - m), e1 = __expf(x1 - m);
    float s = e0 + e1;
#pragma unroll
    for (int d = 1; d < 64; d <<= 1) s += __shfl_xor(s, d);
    if (lane == 0) reds[wave] = s;
    __syncthreads();
    s = reds[0] + reds[1] + reds[2] + reds[3];
    float inv = __builtin_amdgcn_rcpf(s);
    p[tid] = e0 * inv;
    p[tid + 256] = e1 * inv;
}

// ---------------- K4: out[b][i][n] = sum_j attn[b][i][j] * v[b][j][n] ----------------
__global__ __launch_bounds__(256) void out_gemm(const float* __restrict__ attn,
                                                const float* __restrict__ v,
                                                float* __restrict__ out) {
    const int BK = 16;
    __shared__ float As[BK][68];  // As[kk][m] = attn[i0+m][k0+kk]
    __shared__ float Bs[BK][68];  // Bs[kk][n] = v[k0+kk][n0+n]
    int b = blockIdx.z;
    int i0 = blockIdx.y * 64;
    int n0 = blockIdx.x * 64;
    const float* Ab = attn + (size_t)b * QN * KVN;
    const float* Vb = v + (size_t)b * KVN * VD_;
    int tid = threadIdx.x;
    int tm = tid >> 4, tn = tid & 15;
    float c[4][4] = {};
    for (int k0 = 0; k0 < KVN; k0 += BK) {
#pragma unroll
        for (int i = 0; i < 4; ++i) {
            int l = tid + i * 256;
            int m = l >> 4, kk = l & 15;
            As[kk][m] = Ab[(size_t)(i0 + m) * KVN + k0 + kk];
            int n = l & 63, kk2 = l >> 6;
            Bs[kk2][n] = Vb[(size_t)(k0 + kk2) * VD_ + n0 + n];
        }
        __syncthreads();
#pragma unroll
        for (int kk = 0; kk < BK; ++kk) {
            float4 a = *(const float4*)&As[kk][tm * 4];
            float4 bv = *(const float4*)&Bs[kk][tn * 4];
            c[0][0] = __builtin_fmaf(a.x, bv.x, c[0][0]);
            c[0][1] = __builtin_fmaf(a.x, bv.y, c[0][1]);
            c[0][2] = __builtin_fmaf(a.x, bv.z, c[0][2]);
            c[0][3] = __builtin_fmaf(a.x, bv.w, c[0][3]);
            c[1][0] = __builtin_fmaf(a.y, bv.x, c[1][0]);
            c[1][1] = __builtin_fmaf(a.y, bv.y, c[1][1]);
            c[1][2] = __builtin_fmaf(a.y, bv.z, c[1][2]);
            c[1][3] = __builtin_fmaf(a.y, bv.w, c[1][3]);
            c[2][0] = __builtin_fmaf(a.z, bv.x, c[2][0]);
            c[2][1] = __builtin_fmaf(a.z, bv.y, c[2][1]);
            c[2][2] = __builtin_fmaf(a.z, bv.z, c[2][2]);
            c[2][3] = __builtin_fmaf(a.z, bv.w, c[2][3]);
            c[3][0] = __builtin_fmaf(a.w, bv.x, c[3][0]);
            c[3][1] = __builtin_fmaf(a.w, bv.y, c[3][1]);
            c[3][2] = __builtin_fmaf(a.w, bv.z, c[3][2]);
            c[3][3] = __builtin_fmaf(a.w, bv.w, c[3][3]);
        }
        __syncthreads();
    }
#pragma unroll
    for (int ii = 0; ii < 4; ++ii) {
        float4 r;
        r.x = c[ii][0]; r.y = c[ii][1]; r.z = c[ii][2]; r.w = c[ii][3];
        *(float4*)&out[((size_t)b * QN + i0 + tm * 4 + ii) * VD_ + n0 + tn * 4] = r;
    }
}

extern "C" void kernel_launch(void* const* d_in, const int* in_sizes, int n_in,
                              void* d_out, int out_size, void* d_ws, size_t ws_size,
                              hipStream_t stream) {
    const float* q  = (const float*)d_in[0];
    const float* k  = (const float*)d_in[1];
    const float* v  = (const float*)d_in[2];
    const float* Wq = (const float*)d_in[3];
    const float* Wk = (const float*)d_in[4];
    const float* wv = (const float*)d_in[5];
    float* out  = (float*)d_out;                       // [B, QN, VD]
    float* attn = out + (size_t)B_ * QN * VD_;         // [B, QN, KVN] (also raw-score scratch)
    float* qh = (float*)d_ws;                          // [B*QN, H]
    float* kh = qh + (size_t)B_ * QN * H_;             // [B*KVN, H]

    dim3 gp(H_ / 64, (B_ * QN) / 64);
    proj_nt<<<gp, 256, 0, stream>>>(q, Wq, qh);
    proj_nt<<<gp, 256, 0, stream>>>(k, Wk, kh);

    dim3 gs(KVN / 64, QN / 32, B_);
    scores_kernel<<<gs, 256, 0, stream>>>(qh, kh, wv, attn);

    softmax_kernel<<<B_ * QN, 256, 0, stream>>>(attn);

    dim3 go(VD_ / 64, QN / 64, B_);
    out_gemm<<<go, 256, 0, stream>>>(attn, v, out);
}

// Round 2
// 115.449 us; speedup vs baseline: 1.5108x; 1.5108x over previous
//
#include <hip/hip_runtime.h>

#define B_ 4
#define QN 512
#define KVN 512
#define QD_ 512
#define H_ 256
#define VD_ 256

// ---------------- K1: fused projection GEMM (z=0: q·Wq, z=1: k·Wk) ----------------
// C[r][h] = (sum_d A[r][d] * W[h][d]) * 2*log2(e)   (prescale for scores' exp2)
__global__ __launch_bounds__(256) void proj_fused(const float* __restrict__ q,
                                                  const float* __restrict__ k,
                                                  const float* __restrict__ Wq,
                                                  const float* __restrict__ Wk,
                                                  float* __restrict__ qh,
                                                  float* __restrict__ kh) {
    const float* A = blockIdx.z ? k : q;
    const float* W = blockIdx.z ? Wk : Wq;
    float* C = blockIdx.z ? kh : qh;
    __shared__ float As[16][68];  // As[kk][m], 64 rows
    __shared__ float Ws[16][36];  // Ws[kk][n], 32 cols
    int r0 = blockIdx.y * 64;
    int h0 = blockIdx.x * 32;
    int tid = threadIdx.x;
    int tm = tid >> 4, tn = tid & 15;
    float c[4][2] = {};
    for (int k0 = 0; k0 < QD_; k0 += 16) {
#pragma unroll
        for (int i = 0; i < 4; ++i) {
            int l = tid + i * 256;
            int m = l >> 4, kk = l & 15;
            As[kk][m] = A[(size_t)(r0 + m) * QD_ + k0 + kk];
        }
#pragma unroll
        for (int i = 0; i < 2; ++i) {
            int l = tid + i * 256;
            int n = l >> 4, kk = l & 15;
            Ws[kk][n] = W[(size_t)(h0 + n) * QD_ + k0 + kk];
        }
        __syncthreads();
#pragma unroll
        for (int kk = 0; kk < 16; ++kk) {
            float4 a = *(const float4*)&As[kk][tm * 4];
            float2 b = *(const float2*)&Ws[kk][tn * 2];
            c[0][0] = __builtin_fmaf(a.x, b.x, c[0][0]);
            c[0][1] = __builtin_fmaf(a.x, b.y, c[0][1]);
            c[1][0] = __builtin_fmaf(a.y, b.x, c[1][0]);
            c[1][1] = __builtin_fmaf(a.y, b.y, c[1][1]);
            c[2][0] = __builtin_fmaf(a.z, b.x, c[2][0]);
            c[2][1] = __builtin_fmaf(a.z, b.y, c[2][1]);
            c[3][0] = __builtin_fmaf(a.w, b.x, c[3][0]);
            c[3][1] = __builtin_fmaf(a.w, b.y, c[3][1]);
        }
        __syncthreads();
    }
    const float cs = 2.8853900817779268f;  // 2*log2(e)
#pragma unroll
    for (int ii = 0; ii < 4; ++ii) {
        float2 r;
        r.x = c[ii][0] * cs;
        r.y = c[ii][1] * cs;
        *(float2*)&C[(size_t)(r0 + tm * 4 + ii) * H_ + h0 + tn * 2] = r;
    }
}

// ---------------- K2: sc[b][i][j] = -2 * sum_h wv[h] * rcp(exp2(qh'+kh') + 1) ----------
// (equals scores minus the row-constant sum(wv); softmax is shift-invariant)
__global__ __launch_bounds__(256) void scores_kernel(const float* __restrict__ qh,
                                                     const float* __restrict__ kh,
                                                     const float* __restrict__ wv,
                                                     float* __restrict__ sc) {
    __shared__ float qs[32][65];
    __shared__ float ks[32][65];
    __shared__ float wvs[H_];
    int b = blockIdx.z;
    int i0 = blockIdx.y * 32;
    int j0 = blockIdx.x * 32;
    int tid = threadIdx.x;
    int ti = tid >> 4, tj = tid & 15;
    wvs[tid] = wv[tid];  // blockDim == H_ == 256
    float acc[2][2] = {};
    for (int h0 = 0; h0 < H_; h0 += 64) {
#pragma unroll
        for (int t = 0; t < 8; ++t) {
            int l = tid + t * 256;
            int row = l >> 6, hh = l & 63;
            qs[row][hh] = qh[(size_t)(b * QN + i0 + row) * H_ + h0 + hh];
            ks[row][hh] = kh[(size_t)(b * KVN + j0 + row) * H_ + h0 + hh];
        }
        __syncthreads();
#pragma unroll 4
        for (int h = 0; h < 64; ++h) {
            float w = wvs[h0 + h];
            float q0 = qs[ti][h], q1 = qs[ti + 16][h];
            float k0 = ks[tj][h], k1 = ks[tj + 16][h];
            float e00 = __builtin_amdgcn_exp2f(q0 + k0);
            float e01 = __builtin_amdgcn_exp2f(q0 + k1);
            float e10 = __builtin_amdgcn_exp2f(q1 + k0);
            float e11 = __builtin_amdgcn_exp2f(q1 + k1);
            acc[0][0] = __builtin_fmaf(w, __builtin_amdgcn_rcpf(e00 + 1.0f), acc[0][0]);
            acc[0][1] = __builtin_fmaf(w, __builtin_amdgcn_rcpf(e01 + 1.0f), acc[0][1]);
            acc[1][0] = __builtin_fmaf(w, __builtin_amdgcn_rcpf(e10 + 1.0f), acc[1][0]);
            acc[1][1] = __builtin_fmaf(w, __builtin_amdgcn_rcpf(e11 + 1.0f), acc[1][1]);
        }
        __syncthreads();
    }
#pragma unroll
    for (int ii = 0; ii < 2; ++ii)
#pragma unroll
        for (int jj = 0; jj < 2; ++jj)
            sc[(size_t)(b * QN + i0 + ti + 16 * ii) * KVN + j0 + tj + 16 * jj] =
                -2.0f * acc[ii][jj];
}

// ---------------- K3: in-place softmax over last dim (512) ----------------
__global__ __launch_bounds__(256) void softmax_kernel(float* __restrict__ attn) {
    int row = blockIdx.x;
    int tid = threadIdx.x;
    float* p = attn + (size_t)row * KVN;
    float x0 = p[tid], x1 = p[tid + 256];
    float m = fmaxf(x0, x1);
#pragma unroll
    for (int d = 1; d < 64; d <<= 1) m = fmaxf(m, __shfl_xor(m, d));
    __shared__ float redm[4], reds[4];
    int wave = tid >> 6, lane = tid & 63;
    if (lane == 0) redm[wave] = m;
    __syncthreads();
    m = fmaxf(fmaxf(redm[0], redm[1]), fmaxf(redm[2], redm[3]));
    float e0 = __expf(x0 - m), e1 = __expf(x1 - m);
    float s = e0 + e1;
#pragma unroll
    for (int d = 1; d < 64; d <<= 1) s += __shfl_xor(s, d);
    if (lane == 0) reds[wave] = s;
    __syncthreads();
    s = reds[0] + reds[1] + reds[2] + reds[3];
    float inv = __builtin_amdgcn_rcpf(s);
    p[tid] = e0 * inv;
    p[tid + 256] = e1 * inv;
}

// ---------------- K4: out[b][i][n] = sum_j attn[b][i][j] * v[b][j][n] ----------------
__global__ __launch_bounds__(256) void out_gemm(const float* __restrict__ attn,
                                                const float* __restrict__ v,
                                                float* __restrict__ out) {
    __shared__ float As[16][36];  // As[kk][m] = attn[i0+m][k0+kk], 32 rows
    __shared__ float Bs[16][36];  // Bs[kk][n] = v[k0+kk][n0+n], 32 cols
    int b = blockIdx.z;
    int i0 = blockIdx.y * 32;
    int n0 = blockIdx.x * 32;
    const float* Ab = attn + (size_t)b * QN * KVN;
    const float* Vb = v + (size_t)b * KVN * VD_;
    int tid = threadIdx.x;
    int tm = tid >> 4, tn = tid & 15;
    float c[2][2] = {};
    for (int k0 = 0; k0 < KVN; k0 += 16) {
#pragma unroll
        for (int i = 0; i < 2; ++i) {
            int l = tid + i * 256;
            int m = l >> 4, kk = l & 15;
            As[kk][m] = Ab[(size_t)(i0 + m) * KVN + k0 + kk];
            int n = l & 31, kk2 = l >> 5;
            Bs[kk2][n] = Vb[(size_t)(k0 + kk2) * VD_ + n0 + n];
        }
        __syncthreads();
#pragma unroll
        for (int kk = 0; kk < 16; ++kk) {
            float2 a = *(const float2*)&As[kk][tm * 2];
            float2 bv = *(const float2*)&Bs[kk][tn * 2];
            c[0][0] = __builtin_fmaf(a.x, bv.x, c[0][0]);
            c[0][1] = __builtin_fmaf(a.x, bv.y, c[0][1]);
            c[1][0] = __builtin_fmaf(a.y, bv.x, c[1][0]);
            c[1][1] = __builtin_fmaf(a.y, bv.y, c[1][1]);
        }
        __syncthreads();
    }
#pragma unroll
    for (int ii = 0; ii < 2; ++ii) {
        float2 r;
        r.x = c[ii][0];
        r.y = c[ii][1];
        *(float2*)&out[((size_t)b * QN + i0 + tm * 2 + ii) * VD_ + n0 + tn * 2] = r;
    }
}

extern "C" void kernel_launch(void* const* d_in, const int* in_sizes, int n_in,
                              void* d_out, int out_size, void* d_ws, size_t ws_size,
                              hipStream_t stream) {
    const float* q  = (const float*)d_in[0];
    const float* k  = (const float*)d_in[1];
    const float* v  = (const float*)d_in[2];
    const float* Wq = (const float*)d_in[3];
    const float* Wk = (const float*)d_in[4];
    const float* wv = (const float*)d_in[5];
    float* out  = (float*)d_out;                   // [B, QN, VD]
    float* attn = out + (size_t)B_ * QN * VD_;     // [B, QN, KVN]
    float* qh = (float*)d_ws;                      // [B*QN, H] (prescaled by 2*log2e)
    float* kh = qh + (size_t)B_ * QN * H_;         // [B*KVN, H] (prescaled)

    proj_fused<<<dim3(H_ / 32, (B_ * QN) / 64, 2), 256, 0, stream>>>(q, k, Wq, Wk, qh, kh);
    scores_kernel<<<dim3(KVN / 32, QN / 32, B_), 256, 0, stream>>>(qh, kh, wv, attn);
    softmax_kernel<<<B_ * QN, 256, 0, stream>>>(attn);
    out_gemm<<<dim3(VD_ / 32, QN / 32, B_), 256, 0, stream>>>(attn, v, out);
}